// Round 8
// baseline (357.215 us; speedup 1.0000x reference)
//
#include <hip/hip_runtime.h>
#include <hip/hip_bf16.h>
#include <math.h>

typedef float f32x4 __attribute__((ext_vector_type(4)));
typedef short short8 __attribute__((ext_vector_type(8)));
typedef short short4v __attribute__((ext_vector_type(4)));

#define BA 1024          // B*L
#define QD 512           // QUERY_DIM
#define CD 1576          // CTX_DIM
#define NV 36            // N_VIEWS
#define KVD 112
#define HLD 2200         // 1576 + 512 + 112  (bf16 elements)
#define WKLD 2476        // W_key leading dim
#define CD4 394          // CD / 4
#define LDP 72           // LDS pitch (shorts): 144B rows rotate 4 banks

// ---------------- pano affinity, closed form ----------------
__device__ __forceinline__ float pano_adj(int v, int w) {
    if (v == w) return 1.f;
    int rv = v / 12, rw = w / 12;
    int dr = rv - rw; if (dr < 0) dr = -dr;
    if (dr > 1) return 0.f;
    int dc = ((v % 12) - (w % 12) + 12) % 12;
    if (dc == 1 || dc == 11) return 1.f;
    if (dc == 0 && dr == 1) return 1.f;
    return 0.f;
}

__device__ __forceinline__ float pano_entry(int i, int j) {
    if (i == j) return 1.0f;
    float val;
    if (i >= 1 && i <= 34 && j >= 1 && j <= 34) {
        float wr[3] = {0.25f, 0.5f, 0.25f};
        val = 0.f;
        #pragma unroll
        for (int di = 0; di < 3; ++di)
            #pragma unroll
            for (int dj = 0; dj < 3; ++dj)
                val += wr[di] * wr[dj] * pano_adj(i - 1 + di, j - 1 + dj);
    } else {
        val = pano_adj(i, j);
    }
    return (val == 0.f) ? 0.01f : val;
}

__device__ __forceinline__ short f2bf(float f) {
    __hip_bfloat16 h = __float2bfloat16(f);   // RTNE
    union { __hip_bfloat16 b; short s; } u; u.b = h; return u.s;
}

// ---------------- 512-thread MFMA GEMM tile (NT), internal LDS -----------
// C[m,n] = sum_k A[m,k] * B[n,k].  Tile TM x 64, BK=64, 8 waves.
// TM=128: wave 64x16 (4 frags); TM=64: 32x16 (2); TM=32: 16x16 (1).
// __noinline__ + own __shared__: register/LDS firewall vs caller phases.
template<int TM, bool ABF16, bool BBF16, bool CBF16, bool TANH>
__device__ __noinline__ void gemm_tile512(
        const void* __restrict__ Av, const void* __restrict__ Bv,
        void* __restrict__ Cv, int m0, int n0, int N, int K,
        int lda, int ldb, int ldc) {
    __shared__ __align__(16) short As[2][TM * LDP];
    __shared__ __align__(16) short Bs[2][64 * LDP];
    const int t = threadIdx.x;
    const int lane = t & 63, w = t >> 6;
    const float* Af = (const float*)Av; const short* Ah = (const short*)Av;
    const float* Bf = (const float*)Bv; const short* Bh = (const short*)Bv;

    constexpr int AG = (TM == 128) ? 2 : 1;
    const int ar  = (TM == 128) ? (t >> 2) : (t >> 3);
    const int akq = (TM == 128) ? ((t & 3) * 16) : ((t & 7) * 8);
    const bool astage = (TM >= 64) || (t < TM * 8);
    const int br = t >> 3, bkq = (t & 7) * 8;

    short8 abuf[AG], bbuf;

    auto loadA = [&](int k0) {
        if (!astage) return;
        const size_t ro = (size_t)(m0 + ar) * lda;
        #pragma unroll
        for (int g = 0; g < AG; ++g) {
            const int k = k0 + akq + g * 8;
            short8 z;
            if (ABF16) {
                if (k + 8 <= K) z = *(const short8*)(Ah + ro + k);
                else {
                    #pragma unroll
                    for (int j = 0; j < 8; ++j) z[j] = (k + j < K) ? Ah[ro + k + j] : (short)0;
                }
            } else {
                if (k + 8 <= K) {
                    f32x4 v0 = *(const f32x4*)(Af + ro + k);
                    f32x4 v1 = *(const f32x4*)(Af + ro + k + 4);
                    z[0]=f2bf(v0.x); z[1]=f2bf(v0.y); z[2]=f2bf(v0.z); z[3]=f2bf(v0.w);
                    z[4]=f2bf(v1.x); z[5]=f2bf(v1.y); z[6]=f2bf(v1.z); z[7]=f2bf(v1.w);
                } else {
                    #pragma unroll
                    for (int j = 0; j < 8; ++j) z[j] = (k + j < K) ? f2bf(Af[ro + k + j]) : (short)0;
                }
            }
            abuf[g] = z;
        }
    };
    auto loadB = [&](int k0) {
        const int rn = n0 + br;
        const size_t ro = (size_t)rn * ldb;
        const bool ok = rn < N;
        const int k = k0 + bkq;
        short8 z;
        if (BBF16) {
            if (ok && k + 8 <= K) z = *(const short8*)(Bh + ro + k);
            else {
                #pragma unroll
                for (int j = 0; j < 8; ++j) z[j] = (ok && k + j < K) ? Bh[ro + k + j] : (short)0;
            }
        } else {
            if (ok && k + 8 <= K) {
                f32x4 v0 = *(const f32x4*)(Bf + ro + k);
                f32x4 v1 = *(const f32x4*)(Bf + ro + k + 4);
                z[0]=f2bf(v0.x); z[1]=f2bf(v0.y); z[2]=f2bf(v0.z); z[3]=f2bf(v0.w);
                z[4]=f2bf(v1.x); z[5]=f2bf(v1.y); z[6]=f2bf(v1.z); z[7]=f2bf(v1.w);
            } else {
                #pragma unroll
                for (int j = 0; j < 8; ++j) z[j] = (ok && k + j < K) ? f2bf(Bf[ro + k + j]) : (short)0;
            }
        }
        bbuf = z;
    };
    auto writeAB = [&](int buf) {
        if (astage) {
            #pragma unroll
            for (int g = 0; g < AG; ++g)
                *(short8*)&As[buf][ar * LDP + akq + g * 8] = abuf[g];
        }
        *(short8*)&Bs[buf][br * LDP + bkq] = bbuf;
    };

    constexpr int MRF = TM / 32;
    const int wm = (w >> 2) * (TM / 2);
    const int wn = (w & 3) * 16;
    const int kb = (lane >> 4) * 8;
    int aidx[MRF];
    #pragma unroll
    for (int i = 0; i < MRF; ++i)
        aidx[i] = (wm + i * 16 + (lane & 15)) * LDP + kb;
    const int bidx = (wn + (lane & 15)) * LDP + kb;

    f32x4 acc[MRF];
    #pragma unroll
    for (int i = 0; i < MRF; ++i) acc[i] = (f32x4){0.f, 0.f, 0.f, 0.f};

    const int nk = (K + 63) / 64;
    loadA(0); loadB(0); writeAB(0);
    __syncthreads();

    int cur = 0;
    for (int kt = 0; kt < nk; ++kt) {
        const bool more = (kt + 1 < nk);
        if (more) { loadA((kt + 1) * 64); loadB((kt + 1) * 64); }

        #pragma unroll
        for (int ks = 0; ks < 2; ++ks) {
            short8 bfr = *(short8*)&Bs[cur][bidx + ks * 32];
            #pragma unroll
            for (int i = 0; i < MRF; ++i) {
                short8 afr = *(short8*)&As[cur][aidx[i] + ks * 32];
                acc[i] = __builtin_amdgcn_mfma_f32_16x16x32_bf16(afr, bfr, acc[i], 0, 0, 0);
            }
        }
        if (more) writeAB(cur ^ 1);
        __syncthreads();
        cur ^= 1;
    }

    // epilogue: C/D map: col = lane&15, row = (lane>>4)*4 + reg
    #pragma unroll
    for (int i = 0; i < MRF; ++i) {
        int row = m0 + wm + i * 16 + (lane >> 4) * 4;
        int col = n0 + wn + (lane & 15);
        if (col < N) {
            #pragma unroll
            for (int r = 0; r < 4; ++r) {
                float v = acc[i][r];
                if (TANH) v = tanhf(v);
                if (CBF16) ((short*)Cv)[(size_t)(row + r) * ldc + col] = f2bf(v);
                else       ((float*)Cv)[(size_t)(row + r) * ldc + col] = v;
            }
        }
    }
}

// ---------------- dispatch A: GEMM1 + weight prep, 256 blocks ------------
__global__ __launch_bounds__(512) void gemm1_prep(
        const float* __restrict__ Q, const float* __restrict__ Wq,
        const float* __restrict__ Wk, const float* __restrict__ Wo,
        short* __restrict__ h, short* __restrict__ wk_t,
        short* __restrict__ wo_b) {
    __shared__ float tile[32][33];
    const int bx = blockIdx.x, t = threadIdx.x;

    if (bx < 128) {
        // Qf = Q @ Wq^T -> h[:, 1576:2088] (bf16)
        gemm_tile512<64, false, false, true, false>(
            (const void*)Q, (const void*)Wq, (void*)(h + CD),
            (bx >> 3) * 64, (bx & 7) * 64, QD, QD, QD, QD, HLD);
    } else if (bx < 208) {
        // Wk[:, :1576] transpose -> wk_t (1576x512 bf16), 800 tiles / 80 blocks
        const int pb = bx - 128;
        const int tx = t & 31, ty = t >> 5;          // 32 x 16
        for (int it = pb; it < 800; it += 80) {
            const int n0 = (it % 50) * 32, q0 = (it / 50) * 32;
            #pragma unroll
            for (int i = 0; i < 2; ++i)
                tile[ty + i * 16][tx] =
                    Wk[(size_t)(q0 + ty + i * 16) * WKLD + n0 + tx];
            __syncthreads();
            #pragma unroll
            for (int i = 0; i < 2; ++i) {
                int n = n0 + ty + i * 16;
                if (n < CD)
                    wk_t[(size_t)n * QD + q0 + tx] = f2bf(tile[tx][ty + i * 16]);
            }
            __syncthreads();
        }
    } else {
        // Wo -> wo_b bf16, 48 blocks
        const int NWO4 = (QD * HLD) / 4;             // 281600
        for (int i = (bx - 208) * 512 + t; i < NWO4; i += 48 * 512) {
            f32x4 v4 = ((const f32x4*)Wo)[i];
            short4v o = { f2bf(v4.x), f2bf(v4.y), f2bf(v4.z), f2bf(v4.w) };
            ((short4v*)wo_b)[i] = o;
        }
    }
}

// ---------------- dispatch B: GEMM2 -> attn -> GEMM4, flag-chained -------
// 256 blocks x 512 thr, 1 block/CU (LDS ~137 KB) -> all co-resident, spins safe.
#define NR 5
#define NCH 7
__global__ __launch_bounds__(512, 1) void fused_paw(
        const float* __restrict__ V, const int* __restrict__ tid,
        const float* __restrict__ kv, const short* __restrict__ wk_t,
        const short* __restrict__ wo_b, short* __restrict__ h,
        float* __restrict__ P, float* __restrict__ out,
        float* __restrict__ attn_out, int* __restrict__ gcnt,
        int* __restrict__ acnt) {
    const int bx = blockIdx.x, t = threadIdx.x;
    const int w = t >> 6, lane = t & 63;
    __shared__ float en[NV];
    __shared__ float ag[NV];
    __shared__ __align__(16) f32x4 part[8 * 448];   // 57 KB

    // ---- phase 1: GEMM2. group grp (32 blocks) produces P rows 128*grp..+127
    const int grp = bx >> 5, nb = bx & 31;
    if (nb < 25) {
        gemm_tile512<128, true, true, false, false>(
            (const void*)(h + CD), (const void*)wk_t, (void*)P,
            grp * 128, nb * 64, CD, QD, HLD, QD, CD);
        __threadfence();
        __syncthreads();
        if (t == 0)
            __hip_atomic_fetch_add(&gcnt[grp], 1, __ATOMIC_RELEASE, __HIP_MEMORY_SCOPE_AGENT);
    }

    // ---- phase 2: one-pass attention (V register-resident, 4 b's/block)
    f32x4 p[NCH];
    f32x4 v[NR][NCH];

    auto load_v = [&](int b) {
        const f32x4* V4 = (const f32x4*)(V + (size_t)b * NV * CD);
        #pragma unroll
        for (int r = 0; r < NR; ++r) {
            int n = w + 8 * r;
            #pragma unroll
            for (int j = 0; j < NCH; ++j) {
                int c = lane + 64 * j;
                v[r][j] = (n < NV && c < CD4) ? V4[(size_t)n * CD4 + c]
                                              : (f32x4){0.f, 0.f, 0.f, 0.f};
            }
        }
    };
    auto load_p = [&](int b) {
        const f32x4* P4 = (const f32x4*)(P + (size_t)b * CD);
        #pragma unroll
        for (int j = 0; j < NCH; ++j) {
            int c = lane + 64 * j;
            p[j] = (c < CD4) ? P4[c] : (f32x4){0.f, 0.f, 0.f, 0.f};
        }
    };

    load_v(bx * 4);                 // V stream starts while waiting for P
    if (t == 0) {
        while (__hip_atomic_load(&gcnt[grp], __ATOMIC_ACQUIRE, __HIP_MEMORY_SCOPE_AGENT) < 25)
            __builtin_amdgcn_s_sleep(8);
    }
    __syncthreads();
    __threadfence();
    load_p(bx * 4);

    for (int bi = 0; bi < 4; ++bi) {
        const int b = bx * 4 + bi;

        #pragma unroll
        for (int r = 0; r < NR; ++r) {
            float s = 0.f;
            #pragma unroll
            for (int j = 0; j < NCH; ++j) {
                f32x4 vv = v[r][j], pp = p[j];
                s += vv.x * pp.x + vv.y * pp.y + vv.z * pp.z + vv.w * pp.w;
            }
            #pragma unroll
            for (int off = 32; off > 0; off >>= 1) s += __shfl_xor(s, off);
            int n = w + 8 * r;
            if (lane == 0 && n < NV) en[n] = s;
        }
        __syncthreads();

        if (t < 64) {
            const float SCALE = 0.044194173824159216f;  // 512^-0.5
            float e = (t < NV) ? en[t] * SCALE : -1e30f;
            float m = e;
            #pragma unroll
            for (int off = 32; off > 0; off >>= 1) m = fmaxf(m, __shfl_xor(m, off));
            float pr = (t < NV) ? __expf(e - m) : 0.f;
            float s = pr;
            #pragma unroll
            for (int off = 32; off > 0; off >>= 1) s += __shfl_xor(s, off);
            float a = pr / s;
            if (t < NV) {
                attn_out[(size_t)b * NV + t] = a;
                ag[t] = a * pano_entry(tid[b], t);
            }
        }
        __syncthreads();

        f32x4 acc[NCH];
        #pragma unroll
        for (int j = 0; j < NCH; ++j) acc[j] = (f32x4){0.f, 0.f, 0.f, 0.f};
        #pragma unroll
        for (int r = 0; r < NR; ++r) {
            int n = w + 8 * r;
            float a = (n < NV) ? ag[n] : 0.f;
            #pragma unroll
            for (int j = 0; j < NCH; ++j) {
                acc[j].x += a * v[r][j].x; acc[j].y += a * v[r][j].y;
                acc[j].z += a * v[r][j].z; acc[j].w += a * v[r][j].w;
            }
        }
        #pragma unroll
        for (int j = 0; j < NCH; ++j)
            part[w * 448 + lane + 64 * j] = acc[j];

        if (bi < 3) { load_p(b + 1); load_v(b + 1); }   // overlap tail
        __syncthreads();

        short* hb = h + (size_t)b * HLD;
        if (t < CD4) {
            f32x4 s = part[t];
            #pragma unroll
            for (int w2 = 1; w2 < 8; ++w2) {
                f32x4 q = part[w2 * 448 + t];
                s.x += q.x; s.y += q.y; s.z += q.z; s.w += q.w;
            }
            short4v o = { f2bf(s.x), f2bf(s.y), f2bf(s.z), f2bf(s.w) };
            *(short4v*)(hb + t * 4) = o;
        }
        if (t < KVD)
            hb[CD + QD + t] = f2bf(kv[(size_t)b * KVD + t]);
    }

    // signal h rows done; wait for the 8-block group covering our gemm4 m-tile
    __threadfence();
    __syncthreads();
    if (t == 0) {
        __hip_atomic_fetch_add(&acnt[bx >> 3], 1, __ATOMIC_RELEASE, __HIP_MEMORY_SCOPE_AGENT);
        while (__hip_atomic_load(&acnt[bx >> 3], __ATOMIC_ACQUIRE, __HIP_MEMORY_SCOPE_AGENT) < 8)
            __builtin_amdgcn_s_sleep(8);
    }
    __syncthreads();
    __threadfence();

    // ---- phase 3: GEMM4 (h_tilde = tanh(h @ Wo^T)), 32x64 tile per block
    gemm_tile512<32, true, true, false, true>(
        (const void*)h, (const void*)wo_b, (void*)out,
        (bx >> 3) * 32, (bx & 7) * 64, QD, HLD, HLD, HLD, QD);
}

extern "C" void kernel_launch(void* const* d_in, const int* in_sizes, int n_in,
                              void* d_out, int out_size, void* d_ws, size_t ws_size,
                              hipStream_t stream) {
    const float* Q   = (const float*)d_in[0];
    const float* V   = (const float*)d_in[1];
    // d_in[2] = detect_feats: irrelevant (constant over views + softmax shift invariance)
    const float* kv  = (const float*)d_in[3];
    const int*   tid = (const int*)  d_in[4];
    const float* Wk  = (const float*)d_in[5];
    const float* Wq  = (const float*)d_in[6];
    const float* Wo  = (const float*)d_in[7];

    short* h     = (short*)d_ws;                     // (1024, 2200) bf16
    float* P     = (float*)(h + (size_t)BA * HLD);   // (1024, 1576) f32
    short* wk_t  = (short*)(P + (size_t)BA * CD);    // (1576, 512) bf16 transposed
    short* wo_b  = wk_t + (size_t)CD * QD;           // (512, 2200) bf16
    int*   flags = (int*)(wo_b + (size_t)QD * HLD);  // gcnt[8] + acnt[32]
    int*   gcnt  = flags;
    int*   acnt  = flags + 8;

    float* out      = (float*)d_out;                 // h_tilde (1024, 512)
    float* attn_out = out + (size_t)BA * QD;         // attn    (1024, 36)

    hipMemsetAsync(flags, 0, 40 * sizeof(int), stream);

    // A) GEMM1 + wk transpose + wo convert (one round of 256 blocks)
    gemm1_prep<<<256, 512, 0, stream>>>(Q, Wq, Wk, Wo, h, wk_t, wo_b);

    // B) GEMM2 -> attn -> GEMM4, flag-chained, co-resident persistent blocks
    fused_paw<<<256, 512, 0, stream>>>(V, tid, kv, wk_t, wo_b, h, P, out,
                                       attn_out, gcnt, acnt);
}

// Round 9
// 189.495 us; speedup vs baseline: 1.8851x; 1.8851x over previous
//
#include <hip/hip_runtime.h>
#include <hip/hip_bf16.h>
#include <math.h>

typedef float f32x4 __attribute__((ext_vector_type(4)));
typedef short short8 __attribute__((ext_vector_type(8)));
typedef short short4v __attribute__((ext_vector_type(4)));

#define BA 1024          // B*L
#define QD 512           // QUERY_DIM
#define CD 1576          // CTX_DIM
#define NV 36            // N_VIEWS
#define KVD 112
#define HLD 2200         // Wo leading dim (1576+512+112)
#define WKLD 2476        // W_key leading dim
#define CD4 394          // CD / 4
#define QKLD 624         // qfkv leading dim (512 + 112)
#define LDP 72           // LDS pitch (shorts): 144B rows rotate 4 banks

// ---------------- pano affinity, closed form ----------------
__device__ __forceinline__ float pano_adj(int v, int w) {
    if (v == w) return 1.f;
    int rv = v / 12, rw = w / 12;
    int dr = rv - rw; if (dr < 0) dr = -dr;
    if (dr > 1) return 0.f;
    int dc = ((v % 12) - (w % 12) + 12) % 12;
    if (dc == 1 || dc == 11) return 1.f;
    if (dc == 0 && dr == 1) return 1.f;
    return 0.f;
}

__device__ __forceinline__ float pano_entry(int i, int j) {
    if (i == j) return 1.0f;
    float val;
    if (i >= 1 && i <= 34 && j >= 1 && j <= 34) {
        float wr[3] = {0.25f, 0.5f, 0.25f};
        val = 0.f;
        #pragma unroll
        for (int di = 0; di < 3; ++di)
            #pragma unroll
            for (int dj = 0; dj < 3; ++dj)
                val += wr[di] * wr[dj] * pano_adj(i - 1 + di, j - 1 + dj);
    } else {
        val = pano_adj(i, j);
    }
    return (val == 0.f) ? 0.01f : val;
}

__device__ __forceinline__ short f2bf(float f) {
    __hip_bfloat16 h = __float2bfloat16(f);   // RTNE
    union { __hip_bfloat16 b; short s; } u; u.b = h; return u.s;
}

__device__ __forceinline__ f32x4 bf4f(short4v s) {
    f32x4 r;
    #pragma unroll
    for (int i = 0; i < 4; ++i) {
        union { unsigned u; float f; } c;
        c.u = ((unsigned)(unsigned short)s[i]) << 16;
        r[i] = c.f;
    }
    return r;
}

// ---------------- 512-thread MFMA GEMM tile (NT), LDS passed in ----------
// C[m,n] = sum_k A[m,k] * B[n,k].  Tile TM x 64, BK=64, 8 waves.
// Numerics verified in R8 (passed). Low-register (~110 VGPR) phases only.
template<int TM, bool ABF16, bool BBF16, bool CBF16>
__device__ __noinline__ void gemm_tile512(
        const void* __restrict__ Av, const void* __restrict__ Bv,
        void* __restrict__ Cv, int m0, int n0, int N, int K,
        int lda, int ldb, int ldc,
        short* __restrict__ As, short* __restrict__ Bs) {
    const int t = threadIdx.x;
    const int lane = t & 63, w = t >> 6;
    const float* Af = (const float*)Av; const short* Ah = (const short*)Av;
    const float* Bf = (const float*)Bv; const short* Bh = (const short*)Bv;

    constexpr int AG = (TM == 128) ? 2 : 1;
    const int ar  = (TM == 128) ? (t >> 2) : (t >> 3);
    const int akq = (TM == 128) ? ((t & 3) * 16) : ((t & 7) * 8);
    const int br = t >> 3, bkq = (t & 7) * 8;

    short8 abuf[AG], bbuf;

    auto loadA = [&](int k0) {
        const size_t ro = (size_t)(m0 + ar) * lda;
        #pragma unroll
        for (int g = 0; g < AG; ++g) {
            const int k = k0 + akq + g * 8;
            short8 z;
            if (ABF16) {
                if (k + 8 <= K) z = *(const short8*)(Ah + ro + k);
                else {
                    #pragma unroll
                    for (int j = 0; j < 8; ++j) z[j] = (k + j < K) ? Ah[ro + k + j] : (short)0;
                }
            } else {
                if (k + 8 <= K) {
                    f32x4 v0 = *(const f32x4*)(Af + ro + k);
                    f32x4 v1 = *(const f32x4*)(Af + ro + k + 4);
                    z[0]=f2bf(v0.x); z[1]=f2bf(v0.y); z[2]=f2bf(v0.z); z[3]=f2bf(v0.w);
                    z[4]=f2bf(v1.x); z[5]=f2bf(v1.y); z[6]=f2bf(v1.z); z[7]=f2bf(v1.w);
                } else {
                    #pragma unroll
                    for (int j = 0; j < 8; ++j) z[j] = (k + j < K) ? f2bf(Af[ro + k + j]) : (short)0;
                }
            }
            abuf[g] = z;
        }
    };
    auto loadB = [&](int k0) {
        const int rn = n0 + br;
        const size_t ro = (size_t)rn * ldb;
        const bool ok = rn < N;
        const int k = k0 + bkq;
        short8 z;
        if (BBF16) {
            if (ok && k + 8 <= K) z = *(const short8*)(Bh + ro + k);
            else {
                #pragma unroll
                for (int j = 0; j < 8; ++j) z[j] = (ok && k + j < K) ? Bh[ro + k + j] : (short)0;
            }
        } else {
            if (ok && k + 8 <= K) {
                f32x4 v0 = *(const f32x4*)(Bf + ro + k);
                f32x4 v1 = *(const f32x4*)(Bf + ro + k + 4);
                z[0]=f2bf(v0.x); z[1]=f2bf(v0.y); z[2]=f2bf(v0.z); z[3]=f2bf(v0.w);
                z[4]=f2bf(v1.x); z[5]=f2bf(v1.y); z[6]=f2bf(v1.z); z[7]=f2bf(v1.w);
            } else {
                #pragma unroll
                for (int j = 0; j < 8; ++j) z[j] = (ok && k + j < K) ? f2bf(Bf[ro + k + j]) : (short)0;
            }
        }
        bbuf = z;
    };
    auto writeAB = [&](int buf) {
        #pragma unroll
        for (int g = 0; g < AG; ++g)
            *(short8*)&As[buf * (TM * LDP) + ar * LDP + akq + g * 8] = abuf[g];
        *(short8*)&Bs[buf * (64 * LDP) + br * LDP + bkq] = bbuf;
    };

    constexpr int MRF = TM / 32;
    const int wm = (w >> 2) * (TM / 2);
    const int wn = (w & 3) * 16;
    const int kb = (lane >> 4) * 8;
    int aidx[MRF];
    #pragma unroll
    for (int i = 0; i < MRF; ++i)
        aidx[i] = (wm + i * 16 + (lane & 15)) * LDP + kb;
    const int bidx = (wn + (lane & 15)) * LDP + kb;

    f32x4 acc[MRF];
    #pragma unroll
    for (int i = 0; i < MRF; ++i) acc[i] = (f32x4){0.f, 0.f, 0.f, 0.f};

    const int nk = (K + 63) / 64;
    loadA(0); loadB(0); writeAB(0);
    __syncthreads();

    int cur = 0;
    for (int kt = 0; kt < nk; ++kt) {
        const bool more = (kt + 1 < nk);
        if (more) { loadA((kt + 1) * 64); loadB((kt + 1) * 64); }

        #pragma unroll
        for (int ks = 0; ks < 2; ++ks) {
            short8 bfr = *(short8*)&Bs[cur * (64 * LDP) + bidx + ks * 32];
            #pragma unroll
            for (int i = 0; i < MRF; ++i) {
                short8 afr = *(short8*)&As[cur * (TM * LDP) + aidx[i] + ks * 32];
                acc[i] = __builtin_amdgcn_mfma_f32_16x16x32_bf16(afr, bfr, acc[i], 0, 0, 0);
            }
        }
        if (more) writeAB(cur ^ 1);
        __syncthreads();
        cur ^= 1;
    }

    // epilogue: C/D map: col = lane&15, row = (lane>>4)*4 + reg
    #pragma unroll
    for (int i = 0; i < MRF; ++i) {
        int row = m0 + wm + i * 16 + (lane >> 4) * 4;
        int col = n0 + wn + (lane & 15);
        if (col < N) {
            #pragma unroll
            for (int r = 0; r < 4; ++r) {
                float v = acc[i][r];
                if (CBF16) ((short*)Cv)[(size_t)(row + r) * ldc + col] = f2bf(v);
                else       ((float*)Cv)[(size_t)(row + r) * ldc + col] = v;
            }
        }
    }
}

// ---------------- dispatch A: GEMM1+prep -> flag -> GEMM2+pre ------------
// All phases low-register. 256 blocks x 512 thr, co-resident (LDS ~60 KB).
__global__ __launch_bounds__(512) void fused_front(
        const float* __restrict__ Q, const float* __restrict__ Wq,
        const float* __restrict__ Wk, const float* __restrict__ Wo,
        const float* __restrict__ kv,
        short* __restrict__ qfkv, short* __restrict__ wk_t,
        short* __restrict__ wo_b, short* __restrict__ Pb,
        float* __restrict__ pre, int* __restrict__ cnt) {
    __shared__ __align__(16) short As[2 * 128 * LDP];
    __shared__ __align__(16) short Bs[2 * 64 * LDP];
    __shared__ float tile[32][33];
    const int bx = blockIdx.x, t = threadIdx.x;

    // ---- phase alpha
    if (bx < 128) {
        // Qf = Q @ Wq^T -> qfkv[:, :512] (bf16)
        gemm_tile512<64, false, false, true>(
            (const void*)Q, (const void*)Wq, (void*)qfkv,
            (bx >> 3) * 64, (bx & 7) * 64, QD, QD, QD, QD, QKLD, As, Bs);
    } else if (bx < 208) {
        // Wk[:, :1576] transpose -> wk_t (1576x512 bf16)
        const int pb = bx - 128;
        const int tx = t & 31, ty = t >> 5;          // 32 x 16
        for (int it = pb; it < 800; it += 80) {
            const int n0 = (it % 50) * 32, q0 = (it / 50) * 32;
            #pragma unroll
            for (int i = 0; i < 2; ++i)
                tile[ty + i * 16][tx] =
                    Wk[(size_t)(q0 + ty + i * 16) * WKLD + n0 + tx];
            __syncthreads();
            #pragma unroll
            for (int i = 0; i < 2; ++i) {
                int n = n0 + ty + i * 16;
                if (n < CD)
                    wk_t[(size_t)n * QD + q0 + tx] = f2bf(tile[tx][ty + i * 16]);
            }
            __syncthreads();
        }
    } else {
        // Wo -> wo_b bf16 (full 512x2200), kv -> qfkv[:, 512:624] bf16
        const int NWO4 = (QD * HLD) / 4;             // 281600
        for (int i = (bx - 208) * 512 + t; i < NWO4; i += 48 * 512) {
            f32x4 v4 = ((const f32x4*)Wo)[i];
            short4v o = { f2bf(v4.x), f2bf(v4.y), f2bf(v4.z), f2bf(v4.w) };
            ((short4v*)wo_b)[i] = o;
        }
        const int NKV4 = (BA * KVD) / 4;             // 28672
        for (int i = (bx - 208) * 512 + t; i < NKV4; i += 48 * 512) {
            int b = i / 28, off = (i % 28) * 4;      // 28 f32x4 chunks/row
            f32x4 v4 = *(const f32x4*)(kv + (size_t)b * KVD + off);
            short4v o = { f2bf(v4.x), f2bf(v4.y), f2bf(v4.z), f2bf(v4.w) };
            *(short4v*)(qfkv + (size_t)b * QKLD + QD + off) = o;
        }
    }

    // ---- flag barrier (all 256 blocks co-resident at 1 block/CU)
    __threadfence();
    __syncthreads();
    if (t == 0) {
        __hip_atomic_fetch_add(cnt, 1, __ATOMIC_ACQ_REL, __HIP_MEMORY_SCOPE_AGENT);
        while (__hip_atomic_load(cnt, __ATOMIC_ACQUIRE, __HIP_MEMORY_SCOPE_AGENT) < 256)
            __builtin_amdgcn_s_sleep(2);
    }
    __syncthreads();
    __threadfence();

    // ---- phase beta: job list. jobs 0..199: GEMM2 (128x64 tiles);
    //      jobs 200..327: pre = qfkv @ Wo[:,1576:]^T (64x64 tiles, K=624)
    for (int j = bx; j < 328; j += 256) {
        if (j < 200) {
            gemm_tile512<128, true, true, true>(
                (const void*)qfkv, (const void*)wk_t, (void*)Pb,
                (j / 25) * 128, (j % 25) * 64, CD, QD, QKLD, QD, CD, As, Bs);
        } else {
            int jj = j - 200;
            gemm_tile512<64, true, true, false>(
                (const void*)qfkv, (const void*)(wo_b + CD), (void*)pre,
                (jj >> 3) * 64, (jj & 7) * 64, QD, QKLD, QKLD, HLD, QD, As, Bs);
        }
        __syncthreads();
    }
}

// ---------------- dispatch B: one-pass attention (proven R7 structure) ---
#define NR 5
#define NCH 7
__global__ __launch_bounds__(512, 2) void attn_wc_multib(
        const float* __restrict__ V, const short* __restrict__ Pb,
        const int* __restrict__ tid, short* __restrict__ wc,
        float* __restrict__ attn_out) {
    const int t = threadIdx.x;
    const int w = t >> 6, lane = t & 63;
    __shared__ float en[NV];
    __shared__ float ag[NV];
    __shared__ __align__(16) f32x4 part[8 * 448];   // 57 KB

    f32x4 p[NCH];
    f32x4 v[NR][NCH];

    auto load_v = [&](int b) {
        const f32x4* V4 = (const f32x4*)(V + (size_t)b * NV * CD);
        #pragma unroll
        for (int r = 0; r < NR; ++r) {
            int n = w + 8 * r;
            #pragma unroll
            for (int j = 0; j < NCH; ++j) {
                int c = lane + 64 * j;
                v[r][j] = (n < NV && c < CD4) ? V4[(size_t)n * CD4 + c]
                                              : (f32x4){0.f, 0.f, 0.f, 0.f};
            }
        }
    };
    auto load_p = [&](int b) {
        const short4v* P4 = (const short4v*)(Pb + (size_t)b * CD);
        #pragma unroll
        for (int j = 0; j < NCH; ++j) {
            int c = lane + 64 * j;
            p[j] = (c < CD4) ? bf4f(P4[c]) : (f32x4){0.f, 0.f, 0.f, 0.f};
        }
    };

    load_v(blockIdx.x * 4);
    load_p(blockIdx.x * 4);

    for (int bi = 0; bi < 4; ++bi) {
        const int b = blockIdx.x * 4 + bi;

        #pragma unroll
        for (int r = 0; r < NR; ++r) {
            float s = 0.f;
            #pragma unroll
            for (int j = 0; j < NCH; ++j) {
                f32x4 vv = v[r][j], pp = p[j];
                s += vv.x * pp.x + vv.y * pp.y + vv.z * pp.z + vv.w * pp.w;
            }
            #pragma unroll
            for (int off = 32; off > 0; off >>= 1) s += __shfl_xor(s, off);
            int n = w + 8 * r;
            if (lane == 0 && n < NV) en[n] = s;
        }
        __syncthreads();

        if (t < 64) {
            const float SCALE = 0.044194173824159216f;  // 512^-0.5
            float e = (t < NV) ? en[t] * SCALE : -1e30f;
            float m = e;
            #pragma unroll
            for (int off = 32; off > 0; off >>= 1) m = fmaxf(m, __shfl_xor(m, off));
            float pr = (t < NV) ? __expf(e - m) : 0.f;
            float s = pr;
            #pragma unroll
            for (int off = 32; off > 0; off >>= 1) s += __shfl_xor(s, off);
            float a = pr / s;
            if (t < NV) {
                attn_out[(size_t)b * NV + t] = a;
                ag[t] = a * pano_entry(tid[b], t);
            }
        }
        __syncthreads();

        f32x4 acc[NCH];
        #pragma unroll
        for (int j = 0; j < NCH; ++j) acc[j] = (f32x4){0.f, 0.f, 0.f, 0.f};
        #pragma unroll
        for (int r = 0; r < NR; ++r) {
            int n = w + 8 * r;
            float a = (n < NV) ? ag[n] : 0.f;
            #pragma unroll
            for (int j = 0; j < NCH; ++j) {
                acc[j].x += a * v[r][j].x; acc[j].y += a * v[r][j].y;
                acc[j].z += a * v[r][j].z; acc[j].w += a * v[r][j].w;
            }
        }
        #pragma unroll
        for (int j = 0; j < NCH; ++j)
            part[w * 448 + lane + 64 * j] = acc[j];

        if (bi < 3) { load_p(b + 1); load_v(b + 1); }   // overlap tail
        __syncthreads();

        short* hb = wc + (size_t)b * CD;
        if (t < CD4) {
            f32x4 s = part[t];
            #pragma unroll
            for (int w2 = 1; w2 < 8; ++w2) {
                f32x4 q = part[w2 * 448 + t];
                s.x += q.x; s.y += q.y; s.z += q.z; s.w += q.w;
            }
            short4v o = { f2bf(s.x), f2bf(s.y), f2bf(s.z), f2bf(s.w) };
            *(short4v*)(hb + t * 4) = o;
        }
    }
}

// ---------------- dispatch C: GEMM4 = tanh(wc @ Wo_c^T + pre) -------------
// 32x32 tiles, 512 blocks (2/CU). K = 1576.
__global__ __launch_bounds__(256) void gemm4_tanh(
        const short* __restrict__ A, const short* __restrict__ B,
        const float* __restrict__ pre, float* __restrict__ C) {
    __shared__ __align__(16) short As[2][32 * LDP];
    __shared__ __align__(16) short Bs[2][32 * LDP];
    const int t = threadIdx.x;
    const int lane = t & 63, w = t >> 6;
    const int n0 = blockIdx.x * 32, m0 = blockIdx.y * 32;
    const int sr = t >> 3, skq = (t & 7) * 8;
    const int K = CD;

    short8 abuf, bbuf;
    auto load = [&](int k0) {
        int k = k0 + skq;
        const short* pa = A + (size_t)(m0 + sr) * CD + k;
        const short* pb = B + (size_t)(n0 + sr) * HLD + k;
        short8 za, zb;
        if (k + 8 <= K) { za = *(const short8*)pa; zb = *(const short8*)pb; }
        else {
            #pragma unroll
            for (int j = 0; j < 8; ++j) {
                za[j] = (k + j < K) ? pa[j] : (short)0;
                zb[j] = (k + j < K) ? pb[j] : (short)0;
            }
        }
        abuf = za; bbuf = zb;
    };
    auto write = [&](int buf) {
        *(short8*)&As[buf][sr * LDP + skq] = abuf;
        *(short8*)&Bs[buf][sr * LDP + skq] = bbuf;
    };

    const int wm = (w >> 1) * 16, wn = (w & 1) * 16;
    const int kb = (lane >> 4) * 8;
    const int aidx = (wm + (lane & 15)) * LDP + kb;
    const int bidx = (wn + (lane & 15)) * LDP + kb;

    const int row = m0 + wm + (lane >> 4) * 4;
    const int col = n0 + wn + (lane & 15);
    f32x4 acc;
    #pragma unroll
    for (int r = 0; r < 4; ++r)
        acc[r] = pre[(size_t)(row + r) * QD + col];

    const int nk = (K + 63) / 64;   // 25
    load(0); write(0);
    __syncthreads();

    int cur = 0;
    for (int kt = 0; kt < nk; ++kt) {
        const bool more = (kt + 1 < nk);
        if (more) load((kt + 1) * 64);

        #pragma unroll
        for (int ks = 0; ks < 2; ++ks) {
            short8 afr = *(short8*)&As[cur][aidx + ks * 32];
            short8 bfr = *(short8*)&Bs[cur][bidx + ks * 32];
            acc = __builtin_amdgcn_mfma_f32_16x16x32_bf16(afr, bfr, acc, 0, 0, 0);
        }
        if (more) write(cur ^ 1);
        __syncthreads();
        cur ^= 1;
    }

    #pragma unroll
    for (int r = 0; r < 4; ++r)
        C[(size_t)(row + r) * QD + col] = tanhf(acc[r]);
}

extern "C" void kernel_launch(void* const* d_in, const int* in_sizes, int n_in,
                              void* d_out, int out_size, void* d_ws, size_t ws_size,
                              hipStream_t stream) {
    const float* Q   = (const float*)d_in[0];
    const float* V   = (const float*)d_in[1];
    // d_in[2] = detect_feats: irrelevant (constant over views + softmax shift invariance)
    const float* kv  = (const float*)d_in[3];
    const int*   tid = (const int*)  d_in[4];
    const float* Wk  = (const float*)d_in[5];
    const float* Wq  = (const float*)d_in[6];
    const float* Wo  = (const float*)d_in[7];

    short* qfkv = (short*)d_ws;                      // (1024, 624)  bf16 [Qf|kv]
    short* wc   = qfkv + (size_t)BA * QKLD;          // (1024, 1576) bf16
    short* Pb   = wc   + (size_t)BA * CD;            // (1024, 1576) bf16
    short* wk_t = Pb   + (size_t)BA * CD;            // (1576, 512)  bf16
    short* wo_b = wk_t + (size_t)CD * QD;            // (512, 2200)  bf16
    float* pre  = (float*)(wo_b + (size_t)QD * HLD); // (1024, 512)  f32
    int*   cnt  = (int*)(pre + (size_t)BA * QD);     // 1 flag

    float* out      = (float*)d_out;                 // h_tilde (1024, 512)
    float* attn_out = out + (size_t)BA * QD;         // attn    (1024, 36)

    hipMemsetAsync(cnt, 0, sizeof(int), stream);

    // A) GEMM1 + weight prep -> flag -> GEMM2 + pre-GEMM
    fused_front<<<256, 512, 0, stream>>>(Q, Wq, Wk, Wo, kv,
                                         qfkv, wk_t, wo_b, Pb, pre, cnt);

    // B) energy/softmax/pano/weighted-context (V read once)
    attn_wc_multib<<<BA / 4, 512, 0, stream>>>(V, Pb, tid, wc, attn_out);

    // C) h_tilde = tanh(wc @ Wo_c^T + pre)
    gemm4_tanh<<<dim3(QD / 32, BA / 32), 256, 0, stream>>>(wc, wo_b, pre, out);
}

// Round 10
// 82.341 us; speedup vs baseline: 4.3383x; 2.3014x over previous
//
#include <hip/hip_runtime.h>
#include <hip/hip_bf16.h>
#include <math.h>

typedef float f32x4 __attribute__((ext_vector_type(4)));
typedef short short8 __attribute__((ext_vector_type(8)));
typedef short short4v __attribute__((ext_vector_type(4)));

#define BA 1024          // B*L
#define QD 512           // QUERY_DIM
#define CD 1576          // CTX_DIM
#define NV 36            // N_VIEWS
#define KVD 112
#define HLD 2200         // Wo leading dim (1576+512+112)
#define WKLD 2476        // W_key leading dim
#define CD4 394          // CD / 4
#define QKLD 624         // qfkv leading dim (512 + 112)
#define LDP 72           // LDS pitch (shorts): 144B rows rotate 4 banks

// ---------------- pano affinity, closed form ----------------
__device__ __forceinline__ float pano_adj(int v, int w) {
    if (v == w) return 1.f;
    int rv = v / 12, rw = w / 12;
    int dr = rv - rw; if (dr < 0) dr = -dr;
    if (dr > 1) return 0.f;
    int dc = ((v % 12) - (w % 12) + 12) % 12;
    if (dc == 1 || dc == 11) return 1.f;
    if (dc == 0 && dr == 1) return 1.f;
    return 0.f;
}

__device__ __forceinline__ float pano_entry(int i, int j) {
    if (i == j) return 1.0f;
    float val;
    if (i >= 1 && i <= 34 && j >= 1 && j <= 34) {
        float wr[3] = {0.25f, 0.5f, 0.25f};
        val = 0.f;
        #pragma unroll
        for (int di = 0; di < 3; ++di)
            #pragma unroll
            for (int dj = 0; dj < 3; ++dj)
                val += wr[di] * wr[dj] * pano_adj(i - 1 + di, j - 1 + dj);
    } else {
        val = pano_adj(i, j);
    }
    return (val == 0.f) ? 0.01f : val;
}

__device__ __forceinline__ short f2bf(float f) {
    __hip_bfloat16 h = __float2bfloat16(f);   // RTNE
    union { __hip_bfloat16 b; short s; } u; u.b = h; return u.s;
}

__device__ __forceinline__ f32x4 bf4f(short4v s) {
    f32x4 r;
    #pragma unroll
    for (int i = 0; i < 4; ++i) {
        union { unsigned u; float f; } c;
        c.u = ((unsigned)(unsigned short)s[i]) << 16;
        r[i] = c.f;
    }
    return r;
}

// ---------------- 512-thread MFMA GEMM tile (NT), INLINE (R7-proven) -----
// C[m,n] = sum_k A[m,k] * B[n,k].  Tile 64 x 64, BK=64, 8 waves.
template<bool ABF16, bool BBF16, bool CBF16, bool TANH>
__device__ __forceinline__ void gemm_tile64(
        const void* __restrict__ Av, const void* __restrict__ Bv,
        void* __restrict__ Cv, int m0, int n0, int N, int K,
        int lda, int ldb, int ldc,
        short* __restrict__ As, short* __restrict__ Bs) {
    const int t = threadIdx.x;
    const int lane = t & 63, w = t >> 6;
    const float* Af = (const float*)Av; const short* Ah = (const short*)Av;
    const float* Bf = (const float*)Bv; const short* Bh = (const short*)Bv;

    const int ar = t >> 3, akq = (t & 7) * 8;

    short8 abuf, bbuf;

    auto loadA = [&](int k0) {
        const size_t ro = (size_t)(m0 + ar) * lda;
        const int k = k0 + akq;
        short8 z;
        if (ABF16) {
            if (k + 8 <= K) z = *(const short8*)(Ah + ro + k);
            else {
                #pragma unroll
                for (int j = 0; j < 8; ++j) z[j] = (k + j < K) ? Ah[ro + k + j] : (short)0;
            }
        } else {
            if (k + 8 <= K) {
                f32x4 v0 = *(const f32x4*)(Af + ro + k);
                f32x4 v1 = *(const f32x4*)(Af + ro + k + 4);
                z[0]=f2bf(v0.x); z[1]=f2bf(v0.y); z[2]=f2bf(v0.z); z[3]=f2bf(v0.w);
                z[4]=f2bf(v1.x); z[5]=f2bf(v1.y); z[6]=f2bf(v1.z); z[7]=f2bf(v1.w);
            } else {
                #pragma unroll
                for (int j = 0; j < 8; ++j) z[j] = (k + j < K) ? f2bf(Af[ro + k + j]) : (short)0;
            }
        }
        abuf = z;
    };
    auto loadB = [&](int k0) {
        const int rn = n0 + ar;
        const size_t ro = (size_t)rn * ldb;
        const bool ok = rn < N;
        const int k = k0 + akq;
        short8 z;
        if (BBF16) {
            if (ok && k + 8 <= K) z = *(const short8*)(Bh + ro + k);
            else {
                #pragma unroll
                for (int j = 0; j < 8; ++j) z[j] = (ok && k + j < K) ? Bh[ro + k + j] : (short)0;
            }
        } else {
            if (ok && k + 8 <= K) {
                f32x4 v0 = *(const f32x4*)(Bf + ro + k);
                f32x4 v1 = *(const f32x4*)(Bf + ro + k + 4);
                z[0]=f2bf(v0.x); z[1]=f2bf(v0.y); z[2]=f2bf(v0.z); z[3]=f2bf(v0.w);
                z[4]=f2bf(v1.x); z[5]=f2bf(v1.y); z[6]=f2bf(v1.z); z[7]=f2bf(v1.w);
            } else {
                #pragma unroll
                for (int j = 0; j < 8; ++j) z[j] = (ok && k + j < K) ? f2bf(Bf[ro + k + j]) : (short)0;
            }
        }
        bbuf = z;
    };
    auto writeAB = [&](int buf) {
        *(short8*)&As[buf * (64 * LDP) + ar * LDP + akq] = abuf;
        *(short8*)&Bs[buf * (64 * LDP) + ar * LDP + akq] = bbuf;
    };

    const int wm = (w >> 2) * 32;
    const int wn = (w & 3) * 16;
    const int kb = (lane >> 4) * 8;
    int aidx[2], bidx;
    #pragma unroll
    for (int i = 0; i < 2; ++i)
        aidx[i] = (wm + i * 16 + (lane & 15)) * LDP + kb;
    bidx = (wn + (lane & 15)) * LDP + kb;

    f32x4 acc[2];
    #pragma unroll
    for (int i = 0; i < 2; ++i) acc[i] = (f32x4){0.f, 0.f, 0.f, 0.f};

    const int nk = (K + 63) / 64;
    loadA(0); loadB(0); writeAB(0);
    __syncthreads();

    int cur = 0;
    for (int kt = 0; kt < nk; ++kt) {
        const bool more = (kt + 1 < nk);
        if (more) { loadA((kt + 1) * 64); loadB((kt + 1) * 64); }

        #pragma unroll
        for (int ks = 0; ks < 2; ++ks) {
            short8 bfr = *(short8*)&Bs[cur * (64 * LDP) + bidx + ks * 32];
            #pragma unroll
            for (int i = 0; i < 2; ++i) {
                short8 afr = *(short8*)&As[cur * (64 * LDP) + aidx[i] + ks * 32];
                acc[i] = __builtin_amdgcn_mfma_f32_16x16x32_bf16(afr, bfr, acc[i], 0, 0, 0);
            }
        }
        if (more) writeAB(cur ^ 1);
        __syncthreads();
        cur ^= 1;
    }

    // epilogue: C/D map: col = lane&15, row = (lane>>4)*4 + reg
    #pragma unroll
    for (int i = 0; i < 2; ++i) {
        int row = m0 + wm + i * 16 + (lane >> 4) * 4;
        int col = n0 + wn + (lane & 15);
        if (col < N) {
            #pragma unroll
            for (int r = 0; r < 4; ++r) {
                float v = acc[i][r];
                if (TANH) v = tanhf(v);
                if (CBF16) ((short*)Cv)[(size_t)(row + r) * ldc + col] = f2bf(v);
                else       ((float*)Cv)[(size_t)(row + r) * ldc + col] = v;
            }
        }
    }
}

// ---------------- dispatch A: GEMM1 + weight prep (R7-proven) ------------
__global__ __launch_bounds__(512) void gemm1_prep(
        const float* __restrict__ Q, const float* __restrict__ Wq,
        const float* __restrict__ Wk, const float* __restrict__ Wo,
        const float* __restrict__ kv,
        short* __restrict__ qfkv, short* __restrict__ wk_t,
        short* __restrict__ wo_b) {
    __shared__ __align__(16) short As[2 * 64 * LDP];
    __shared__ __align__(16) short Bs[2 * 64 * LDP];
    __shared__ float tile[32][33];
    const int bx = blockIdx.x, t = threadIdx.x;

    if (bx < 128) {
        // Qf = Q @ Wq^T -> qfkv[:, :512] (bf16)
        gemm_tile64<false, false, true, false>(
            (const void*)Q, (const void*)Wq, (void*)qfkv,
            (bx >> 3) * 64, (bx & 7) * 64, QD, QD, QD, QD, QKLD, As, Bs);
    } else if (bx < 328) {
        // Wk[:, :1576] transpose -> wk_t (1576x512 bf16), 800 tiles / 200 blocks
        const int pb = bx - 128;
        const int tx = t & 31, ty = t >> 5;          // 32 x 16
        for (int it = pb; it < 800; it += 200) {
            const int n0 = (it % 50) * 32, q0 = (it / 50) * 32;
            #pragma unroll
            for (int i = 0; i < 2; ++i)
                tile[ty + i * 16][tx] =
                    Wk[(size_t)(q0 + ty + i * 16) * WKLD + n0 + tx];
            __syncthreads();
            #pragma unroll
            for (int i = 0; i < 2; ++i) {
                int n = n0 + ty + i * 16;
                if (n < CD)
                    wk_t[(size_t)n * QD + q0 + tx] = f2bf(tile[tx][ty + i * 16]);
            }
            __syncthreads();
        }
    } else {
        // Wo -> wo_b bf16 (56 blocks); kv -> qfkv[:, 512:624] bf16
        const int NWO4 = (QD * HLD) / 4;             // 281600
        for (int i = (bx - 328) * 512 + t; i < NWO4; i += 56 * 512) {
            f32x4 v4 = ((const f32x4*)Wo)[i];
            short4v o = { f2bf(v4.x), f2bf(v4.y), f2bf(v4.z), f2bf(v4.w) };
            ((short4v*)wo_b)[i] = o;
        }
        const int NKV4 = (BA * KVD) / 4;             // 28672
        for (int i = (bx - 328) * 512 + t; i < NKV4; i += 56 * 512) {
            int b = i / 28, off = (i % 28) * 4;      // 28 f32x4 chunks/row
            f32x4 v4 = *(const f32x4*)(kv + (size_t)b * KVD + off);
            short4v o = { f2bf(v4.x), f2bf(v4.y), f2bf(v4.z), f2bf(v4.w) };
            *(short4v*)(qfkv + (size_t)b * QKLD + QD + off) = o;
        }
    }
}

// ---------------- 256-thread NT GEMM body (R7's gemm2_nt, inline) --------
template<bool CBF16>
__device__ __forceinline__ void gemm_nt256(
        const short* __restrict__ Ah, const short* __restrict__ Bt,
        void* __restrict__ Cv, int m0, int n0, int N, int K,
        int lda, int ldb, int ldc,
        short (*As)[64 * LDP], short (*Bs)[64 * LDP]) {
    const int t = threadIdx.x;
    const int lane = t & 63, w = t >> 6;

    const int ar = t >> 2, akq = (t & 3) * 16;

    short8 abuf[2], bbuf[2];

    auto loadA = [&](int k0) {
        const size_t ro = (size_t)(m0 + ar) * lda;
        #pragma unroll
        for (int g = 0; g < 2; ++g) {
            int k = k0 + akq + g * 8;
            short8 z;
            if (k + 8 <= K) z = *(const short8*)(Ah + ro + k);
            else {
                #pragma unroll
                for (int j = 0; j < 8; ++j) z[j] = (k + j < K) ? Ah[ro + k + j] : (short)0;
            }
            abuf[g] = z;
        }
    };
    auto loadB = [&](int k0) {
        const int rn = n0 + ar;
        const size_t ro = (size_t)rn * ldb;
        const bool ok = rn < N;
        #pragma unroll
        for (int g = 0; g < 2; ++g) {
            int k = k0 + akq + g * 8;
            short8 z;
            if (ok && k + 8 <= K) z = *(const short8*)(Bt + ro + k);
            else {
                #pragma unroll
                for (int j = 0; j < 8; ++j) z[j] = (ok && k + j < K) ? Bt[ro + k + j] : (short)0;
            }
            bbuf[g] = z;
        }
    };
    auto writeAB = [&](int buf) {
        #pragma unroll
        for (int g = 0; g < 2; ++g) {
            *(short8*)&As[buf][ar * LDP + akq + g * 8] = abuf[g];
            *(short8*)&Bs[buf][ar * LDP + akq + g * 8] = bbuf[g];
        }
    };

    const int wm = (w >> 1) * 32, wn = (w & 1) * 32;
    const int kb = (lane >> 4) * 8;
    int aidx[2], bidx[2];
    #pragma unroll
    for (int i = 0; i < 2; ++i) {
        aidx[i] = (wm + i * 16 + (lane & 15)) * LDP + kb;
        bidx[i] = (wn + i * 16 + (lane & 15)) * LDP + kb;
    }

    f32x4 acc[2][2];
    #pragma unroll
    for (int i = 0; i < 2; ++i)
        #pragma unroll
        for (int j = 0; j < 2; ++j) acc[i][j] = (f32x4){0.f, 0.f, 0.f, 0.f};

    const int nk = (K + 63) / 64;
    loadA(0); loadB(0); writeAB(0);
    __syncthreads();

    int cur = 0;
    for (int kt = 0; kt < nk; ++kt) {
        const bool more = (kt + 1 < nk);
        if (more) { loadA((kt + 1) * 64); loadB((kt + 1) * 64); }

        #pragma unroll
        for (int ks = 0; ks < 2; ++ks) {
            short8 afr[2], bfr[2];
            #pragma unroll
            for (int i = 0; i < 2; ++i) afr[i] = *(short8*)&As[cur][aidx[i] + ks * 32];
            #pragma unroll
            for (int j = 0; j < 2; ++j) bfr[j] = *(short8*)&Bs[cur][bidx[j] + ks * 32];
            #pragma unroll
            for (int i = 0; i < 2; ++i)
                #pragma unroll
                for (int j = 0; j < 2; ++j)
                    acc[i][j] = __builtin_amdgcn_mfma_f32_16x16x32_bf16(afr[i], bfr[j], acc[i][j], 0, 0, 0);
        }
        if (more) writeAB(cur ^ 1);
        __syncthreads();
        cur ^= 1;
    }

    #pragma unroll
    for (int i = 0; i < 2; ++i) {
        #pragma unroll
        for (int j = 0; j < 2; ++j) {
            int row = m0 + wm + i * 16 + (lane >> 4) * 4;
            int col = n0 + wn + j * 16 + (lane & 15);
            if (col < N) {
                #pragma unroll
                for (int r = 0; r < 4; ++r) {
                    if (CBF16) ((short*)Cv)[(size_t)(row + r) * ldc + col] = f2bf(acc[i][j][r]);
                    else       ((float*)Cv)[(size_t)(row + r) * ldc + col] = acc[i][j][r];
                }
            }
        }
    }
}

// ---------------- dispatch B: GEMM2 (400 tiles) + pre (128 tiles) ---------
// pre = qfkv @ Wo[:, 1576:]^T  (K=624) peels Qf/kv columns out of GEMM4.
__global__ __launch_bounds__(256) void gemm2pre(
        const short* __restrict__ qfkv, const short* __restrict__ wk_t,
        const short* __restrict__ wo_b, short* __restrict__ Pb,
        float* __restrict__ pre) {
    __shared__ __align__(16) short As[2][64 * LDP];
    __shared__ __align__(16) short Bs[2][64 * LDP];
    const int bx = blockIdx.x;
    if (bx < 400) {
        gemm_nt256<true>(qfkv, wk_t, (void*)Pb,
                         (bx / 25) * 64, (bx % 25) * 64, CD, QD,
                         QKLD, QD, CD, As, Bs);
    } else {
        const int j = bx - 400;
        gemm_nt256<false>(qfkv, wo_b + CD, (void*)pre,
                          (j >> 3) * 64, (j & 7) * 64, QD, QKLD,
                          QKLD, HLD, QD, As, Bs);
    }
}

// ---------------- dispatch C: one-pass attention (proven) -----------------
#define NR 5
#define NCH 7
__global__ __launch_bounds__(512, 2) void attn_wc_multib(
        const float* __restrict__ V, const short* __restrict__ Pb,
        const int* __restrict__ tid, short* __restrict__ wc,
        float* __restrict__ attn_out) {
    const int t = threadIdx.x;
    const int w = t >> 6, lane = t & 63;
    __shared__ float en[NV];
    __shared__ float ag[NV];
    __shared__ __align__(16) f32x4 part[8 * 448];   // 57 KB

    f32x4 p[NCH];
    f32x4 v[NR][NCH];

    auto load_v = [&](int b) {
        const f32x4* V4 = (const f32x4*)(V + (size_t)b * NV * CD);
        #pragma unroll
        for (int r = 0; r < NR; ++r) {
            int n = w + 8 * r;
            #pragma unroll
            for (int j = 0; j < NCH; ++j) {
                int c = lane + 64 * j;
                v[r][j] = (n < NV && c < CD4) ? V4[(size_t)n * CD4 + c]
                                              : (f32x4){0.f, 0.f, 0.f, 0.f};
            }
        }
    };
    auto load_p = [&](int b) {
        const short4v* P4 = (const short4v*)(Pb + (size_t)b * CD);
        #pragma unroll
        for (int j = 0; j < NCH; ++j) {
            int c = lane + 64 * j;
            p[j] = (c < CD4) ? bf4f(P4[c]) : (f32x4){0.f, 0.f, 0.f, 0.f};
        }
    };

    load_v(blockIdx.x * 4);
    load_p(blockIdx.x * 4);

    for (int bi = 0; bi < 4; ++bi) {
        const int b = blockIdx.x * 4 + bi;

        #pragma unroll
        for (int r = 0; r < NR; ++r) {
            float s = 0.f;
            #pragma unroll
            for (int j = 0; j < NCH; ++j) {
                f32x4 vv = v[r][j], pp = p[j];
                s += vv.x * pp.x + vv.y * pp.y + vv.z * pp.z + vv.w * pp.w;
            }
            #pragma unroll
            for (int off = 32; off > 0; off >>= 1) s += __shfl_xor(s, off);
            int n = w + 8 * r;
            if (lane == 0 && n < NV) en[n] = s;
        }
        __syncthreads();

        if (t < 64) {
            const float SCALE = 0.044194173824159216f;  // 512^-0.5
            float e = (t < NV) ? en[t] * SCALE : -1e30f;
            float m = e;
            #pragma unroll
            for (int off = 32; off > 0; off >>= 1) m = fmaxf(m, __shfl_xor(m, off));
            float pr = (t < NV) ? __expf(e - m) : 0.f;
            float s = pr;
            #pragma unroll
            for (int off = 32; off > 0; off >>= 1) s += __shfl_xor(s, off);
            float a = pr / s;
            if (t < NV) {
                attn_out[(size_t)b * NV + t] = a;
                ag[t] = a * pano_entry(tid[b], t);
            }
        }
        __syncthreads();

        f32x4 acc[NCH];
        #pragma unroll
        for (int j = 0; j < NCH; ++j) acc[j] = (f32x4){0.f, 0.f, 0.f, 0.f};
        #pragma unroll
        for (int r = 0; r < NR; ++r) {
            int n = w + 8 * r;
            float a = (n < NV) ? ag[n] : 0.f;
            #pragma unroll
            for (int j = 0; j < NCH; ++j) {
                acc[j].x += a * v[r][j].x; acc[j].y += a * v[r][j].y;
                acc[j].z += a * v[r][j].z; acc[j].w += a * v[r][j].w;
            }
        }
        #pragma unroll
        for (int j = 0; j < NCH; ++j)
            part[w * 448 + lane + 64 * j] = acc[j];

        if (bi < 3) { load_p(b + 1); load_v(b + 1); }   // overlap tail
        __syncthreads();

        short* hb = wc + (size_t)b * CD;
        if (t < CD4) {
            f32x4 s = part[t];
            #pragma unroll
            for (int w2 = 1; w2 < 8; ++w2) {
                f32x4 q = part[w2 * 448 + t];
                s.x += q.x; s.y += q.y; s.z += q.z; s.w += q.w;
            }
            short4v o = { f2bf(s.x), f2bf(s.y), f2bf(s.z), f2bf(s.w) };
            *(short4v*)(hb + t * 4) = o;
        }
    }
}

// ---------------- dispatch D: GEMM4 = tanh(wc @ Wo_c^T + pre) -------------
// 32x32 tiles, 512 blocks (2/CU). K = 1576.
__global__ __launch_bounds__(256) void gemm4_tanh(
        const short* __restrict__ A, const short* __restrict__ B,
        const float* __restrict__ pre, float* __restrict__ C) {
    __shared__ __align__(16) short As[2][32 * LDP];
    __shared__ __align__(16) short Bs[2][32 * LDP];
    const int t = threadIdx.x;
    const int lane = t & 63, w = t >> 6;
    const int n0 = blockIdx.x * 32, m0 = blockIdx.y * 32;
    const int sr = t >> 3, skq = (t & 7) * 8;
    const int K = CD;

    short8 abuf, bbuf;
    auto load = [&](int k0) {
        int k = k0 + skq;
        const short* pa = A + (size_t)(m0 + sr) * CD + k;
        const short* pb = B + (size_t)(n0 + sr) * HLD + k;
        short8 za, zb;
        if (k + 8 <= K) { za = *(const short8*)pa; zb = *(const short8*)pb; }
        else {
            #pragma unroll
            for (int j = 0; j < 8; ++j) {
                za[j] = (k + j < K) ? pa[j] : (short)0;
                zb[j] = (k + j < K) ? pb[j] : (short)0;
            }
        }
        abuf = za; bbuf = zb;
    };
    auto write = [&](int buf) {
        *(short8*)&As[buf][sr * LDP + skq] = abuf;
        *(short8*)&Bs[buf][sr * LDP + skq] = bbuf;
    };

    const int wm = (w >> 1) * 16, wn = (w & 1) * 16;
    const int kb = (lane >> 4) * 8;
    const int aidx = (wm + (lane & 15)) * LDP + kb;
    const int bidx = (wn + (lane & 15)) * LDP + kb;

    const int row = m0 + wm + (lane >> 4) * 4;
    const int col = n0 + wn + (lane & 15);
    f32x4 acc;
    #pragma unroll
    for (int r = 0; r < 4; ++r)
        acc[r] = pre[(size_t)(row + r) * QD + col];

    const int nk = (K + 63) / 64;   // 25
    load(0); write(0);
    __syncthreads();

    int cur = 0;
    for (int kt = 0; kt < nk; ++kt) {
        const bool more = (kt + 1 < nk);
        if (more) load((kt + 1) * 64);

        #pragma unroll
        for (int ks = 0; ks < 2; ++ks) {
            short8 afr = *(short8*)&As[cur][aidx + ks * 32];
            short8 bfr = *(short8*)&Bs[cur][bidx + ks * 32];
            acc = __builtin_amdgcn_mfma_f32_16x16x32_bf16(afr, bfr, acc, 0, 0, 0);
        }
        if (more) write(cur ^ 1);
        __syncthreads();
        cur ^= 1;
    }

    #pragma unroll
    for (int r = 0; r < 4; ++r)
        C[(size_t)(row + r) * QD + col] = tanhf(acc[r]);
}

extern "C" void kernel_launch(void* const* d_in, const int* in_sizes, int n_in,
                              void* d_out, int out_size, void* d_ws, size_t ws_size,
                              hipStream_t stream) {
    const float* Q   = (const float*)d_in[0];
    const float* V   = (const float*)d_in[1];
    // d_in[2] = detect_feats: irrelevant (constant over views + softmax shift invariance)
    const float* kv  = (const float*)d_in[3];
    const int*   tid = (const int*)  d_in[4];
    const float* Wk  = (const float*)d_in[5];
    const float* Wq  = (const float*)d_in[6];
    const float* Wo  = (const float*)d_in[7];

    short* qfkv = (short*)d_ws;                      // (1024, 624)  bf16 [Qf|kv]
    short* wc   = qfkv + (size_t)BA * QKLD;          // (1024, 1576) bf16
    short* Pb   = wc   + (size_t)BA * CD;            // (1024, 1576) bf16
    short* wk_t = Pb   + (size_t)BA * CD;            // (1576, 512)  bf16
    short* wo_b = wk_t + (size_t)CD * QD;            // (512, 2200)  bf16
    float* pre  = (float*)(wo_b + (size_t)QD * HLD); // (1024, 512)  f32

    float* out      = (float*)d_out;                 // h_tilde (1024, 512)
    float* attn_out = out + (size_t)BA * QD;         // attn    (1024, 36)

    // A) GEMM1 + wk transpose + wo/kv convert
    gemm1_prep<<<384, 512, 0, stream>>>(Q, Wq, Wk, Wo, kv, qfkv, wk_t, wo_b);

    // B) P = qfkv[:, :512] @ wk_t  (bf16 out)  +  pre = qfkv @ Wo[:,1576:]^T
    gemm2pre<<<528, 256, 0, stream>>>(qfkv, wk_t, wo_b, Pb, pre);

    // C) energy/softmax/pano/weighted-context (V read once)
    attn_wc_multib<<<BA / 4, 512, 0, stream>>>(V, Pb, tid, wc, attn_out);

    // D) h_tilde = tanh(wc @ Wo_c^T + pre), K=1576
    gemm4_tanh<<<dim3(QD / 32, BA / 32), 256, 0, stream>>>(wc, wo_b, pre, out);
}